// Round 15
// baseline (53.869 us; speedup 1.0000x reference)
//
#include <hip/hip_runtime.h>

// Problem: x [B=64, C=512, H=28, W=28] fp32.
// Forward math reduces to: out = relu(x - mean_over_C(x)) per (b,h,w).
//
// Round-15: two-kernel fully-contiguous split. Request-rate model from
// rounds 1-14: time = request bytes / rate(segment width); strided kernels
// cap at ~5.1-5.5 TB/s, contiguous runs at ~5.9-6.8 (fillBuffer: 6.85), but
// single-kernel contiguous forces a 306MB two-pass (R13, lost). Split:
//   K1: 392 blocks = 196 tiles x 2 C-halves, 512 thr. Lanes = 64 consecutive
//       f4 positions -> every load is ~1KB contiguous. Lane sums 32 channels,
//       8-wave LDS combine, one 1KB partial store to d_ws (400KB).
//   K2: 392 blocks, no LDS/barrier. Lane: mean = (partial0+partial1)/512,
//       then 32x {contiguous x read (LLC-hot from K1), sub, relu, nt store}.
// HBM bytes ~203MB total at contiguous rate -> predicted 33-37us.

#define B_DIM 64
#define C_DIM 512
#define HW4   196               // f4 groups per (b,c) plane
#define NPOS  12544             // B_DIM * HW4 total f4-position-groups
#define NTIL  196               // NPOS / 64 position tiles
#define NW    8                 // waves per block
#define CPW   32                // channels per lane per half (256/8)

typedef __attribute__((ext_vector_type(4))) float f4;

// ---- K1: per-(tile, C-half) partial channel sums -> ws ----
__global__ __launch_bounds__(512) void kw_reduce(const float* __restrict__ x,
                                                 f4* __restrict__ ws) {
    __shared__ f4 part[NW][64];         // 8 KB

    const int lane = threadIdx.x & 63;
    const int wv   = threadIdx.x >> 6;  // 0..7
    const int t    = blockIdx.x >> 1;   // position tile
    const int h    = blockIdx.x & 1;    // C-half

    const int p    = t * 64 + lane;     // flat f4-position-group
    const int b    = p / HW4;
    const int hw4  = p - b * HW4;
    const int c0   = h * 256 + wv * CPW;

    const f4* __restrict__ xp =
        reinterpret_cast<const f4*>(x) + ((size_t)b * C_DIM + c0) * HW4 + hw4;

    f4 s = (f4)(0.0f);
    #pragma unroll 8
    for (int cc = 0; cc < CPW; ++cc)
        s += xp[(size_t)cc * HW4];

    part[wv][lane] = s;
    __syncthreads();

    if (wv == 0) {
        f4 tot = (f4)(0.0f);
        #pragma unroll
        for (int ww = 0; ww < NW; ++ww) tot += part[ww][lane];
        ws[(size_t)blockIdx.x * 64 + lane] = tot;   // contiguous 1KB store
    }
}

// ---- K2: mean lookup + subtract + relu + contiguous nt store ----
__global__ __launch_bounds__(512) void kw_apply(const float* __restrict__ x,
                                                const f4* __restrict__ ws,
                                                float* __restrict__ out) {
    const int lane = threadIdx.x & 63;
    const int wv   = threadIdx.x >> 6;  // 0..7
    const int t    = blockIdx.x >> 1;
    const int h    = blockIdx.x & 1;

    const int p    = t * 64 + lane;
    const int b    = p / HW4;
    const int hw4  = p - b * HW4;
    const int c0   = h * 256 + wv * CPW;

    const size_t base = ((size_t)b * C_DIM + c0) * HW4 + hw4;
    const f4* __restrict__ xp = reinterpret_cast<const f4*>(x) + base;
    f4* __restrict__ op       = reinterpret_cast<f4*>(out) + base;

    // this position's mean: combine the two half-partials (tiny, L2-hot)
    f4 m = ws[(size_t)(t * 2 + 0) * 64 + lane] + ws[(size_t)(t * 2 + 1) * 64 + lane];
    m *= (1.0f / (float)C_DIM);

    #pragma unroll 8
    for (int cc = 0; cc < CPW; ++cc) {
        f4 v = xp[(size_t)cc * HW4];
        f4 r = v - m;
        r.x = fmaxf(r.x, 0.f);
        r.y = fmaxf(r.y, 0.f);
        r.z = fmaxf(r.z, 0.f);
        r.w = fmaxf(r.w, 0.f);
        __builtin_nontemporal_store(r, &op[(size_t)cc * HW4]);
    }
}

extern "C" void kernel_launch(void* const* d_in, const int* in_sizes, int n_in,
                              void* d_out, int out_size, void* d_ws, size_t ws_size,
                              hipStream_t stream) {
    const float* x  = (const float*)d_in[0];   // [B, C, H, W] fp32
    float* out = (float*)d_out;
    f4* ws     = (f4*)d_ws;                    // 392*64*16B = 400 KB partials

    dim3 block(512);
    dim3 grid(NTIL * 2);                       // 392 blocks
    hipLaunchKernelGGL(kw_reduce, grid, block, 0, stream, x, ws);
    hipLaunchKernelGGL(kw_apply,  grid, block, 0, stream, x, ws, out);
}